// Round 1
// baseline (92.817 us; speedup 1.0000x reference)
//
#include <hip/hip_runtime.h>
#include <cfloat>
#include <cmath>

// x[B,W,L], shapelets[N,L], cls_w[1,N], cls_b[1]
constexpr int B = 64;
constexpr int W = 256;
constexpr int N = 128;
constexpr int L = 64;
constexpr int NC = 16;        // window-chunks per batch element
constexpr int WPB = W / NC;   // 16 windows per block

// Arrival counters for the last-block-per-b head. Zero-initialized at module
// load; the last block restores its counter to 0 so every launch (and every
// rocprof counter-replay) starts from a clean state. No spin-waits anywhere,
// so no deadlock risk; only the last-arriving block proceeds to the tail.
__device__ int g_cnt[B];

// VALU-pipe cross-lane add (DPP), avoiding the DS pipe entirely.
// CTRL: 0xB1 = quad_perm xor1, 0x4E = quad_perm xor2,
//       0x141 = row_half_mirror (xor-4 class), 0x140 = row_mirror (xor-8).
template <int CTRL>
__device__ __forceinline__ float dpp_add(float v) {
  return v + __int_as_float(__builtin_amdgcn_update_dpp(
                 0, __float_as_int(v), CTRL, 0xF, 0xF, true));
}

// ---------------------------------------------------------------------------
// FUSED kernel: per-(b, chunk) compute  min_w ( ||x_w||^2 - 2 <x_w, s_n> )
// for all 128 shapelets, add ||s_n||^2 (computed in-block via the same DPP
// tree), write the chunk-min to part[b, c, :], then device-scope arrive.
// The last block for each b runs the classifier head (min over chunks is
// already folded per-chunk; here: sqrt -> dot(cls_w) -> sigmoid).
//
// Rationale: rocprof shows the timed stream is {256MiB poison-fill (40.6us,
// harness-fixed) -> k1 -> k2}; the kernels are ~8-10us of throughput work, so
// the serialized-dispatch overhead is the remaining lever. Fusing removes one
// dispatch + one inter-kernel drain.
//
// R9 post-mortem guard (previous session: appending a tail made regalloc
// under-budget VGPR=32 and spill the hot loop -> 95us):
//  - tail is alloca-free / array-free / fully unrolled,
//  - amdgpu_waves_per_eu(4,4): grid is exactly 4 blocks/CU (1024 blocks),
//    so capping at 4 waves/EU costs nothing and gives regalloc a 128-VGPR
//    budget instead of an occupancy-chasing 32.
// grid = B*NC = 1024, block = 256.
// ---------------------------------------------------------------------------
__global__ __launch_bounds__(256)
__attribute__((amdgpu_waves_per_eu(4, 4)))
void shapelet_fused_kernel(const float* __restrict__ x,
                           const float* __restrict__ shp,
                           const float* __restrict__ cls_w,
                           const float* __restrict__ cls_b,
                           float* __restrict__ part,
                           float* __restrict__ out) {
  __shared__ float xs[WPB * L];   // 4 KB
  __shared__ float xnorm_s[WPB];
  __shared__ int s_last;
  __shared__ float red[4];

  const int b = blockIdx.x >> 4;
  const int c = blockIdx.x & 15;
  const int tid = threadIdx.x;
  const int oct = tid & 7;        // eighth-of-row owned by this lane
  const int grp = tid >> 3;       // 0..31 -> shapelets 4*grp..4*grp+3
  const int n0 = grp * 4;

  // --- Stage x[b, c*16:(c+1)*16, :]: one float4/thread; ||x_w||^2 via a
  // 16-lane DPP reduction (16 float4 per window) — zero DS-pipe swizzles.
  {
    const float4* xg =
        (const float4*)(x + ((size_t)b * W + (size_t)c * WPB) * L);
    float4 v = xg[tid];
    ((float4*)xs)[tid] = v;
    float p = v.x * v.x + v.y * v.y + v.z * v.z + v.w * v.w;
    p = dpp_add<0xB1>(p);    // xor1 (quad)
    p = dpp_add<0x4E>(p);    // xor2 (quad)
    p = dpp_add<0x141>(p);   // 4<->8 within row of 16
    p = dpp_add<0x140>(p);   // mirror row of 16
    if ((tid & 15) == 0) xnorm_s[tid >> 4] = p;
  }

  // --- Eighth-rows of 4 shapelets: 8 NAMED float4 (32 VGPRs). No arrays.
  const float4* g0 = (const float4*)(shp + (size_t)(n0 + 0) * L + oct * 8);
  const float4* g1 = (const float4*)(shp + (size_t)(n0 + 1) * L + oct * 8);
  const float4* g2 = (const float4*)(shp + (size_t)(n0 + 2) * L + oct * 8);
  const float4* g3 = (const float4*)(shp + (size_t)(n0 + 3) * L + oct * 8);
  const float4 s0a = g0[0], s0b = g0[1];
  const float4 s1a = g1[0], s1b = g1[1];
  const float4 s2a = g2[0], s2b = g2[1];
  const float4 s3a = g3[0], s3b = g3[1];

  // --- ||s_n||^2 once per block via the same 8-lane DPP tree (4 extra live
  // VGPRs through the loop; ~60 one-off VALU ops). min_w(.) + q_n is applied
  // at the part-write, replacing kernel 2's recompute.
  float q0 = s0a.x * s0a.x + s0a.y * s0a.y;
  float q1 = s1a.x * s1a.x + s1a.y * s1a.y;
  float q2 = s2a.x * s2a.x + s2a.y * s2a.y;
  float q3 = s3a.x * s3a.x + s3a.y * s3a.y;
  q0 = fmaf(s0a.z, s0a.z, q0); q0 = fmaf(s0a.w, s0a.w, q0);
  q1 = fmaf(s1a.z, s1a.z, q1); q1 = fmaf(s1a.w, s1a.w, q1);
  q2 = fmaf(s2a.z, s2a.z, q2); q2 = fmaf(s2a.w, s2a.w, q2);
  q3 = fmaf(s3a.z, s3a.z, q3); q3 = fmaf(s3a.w, s3a.w, q3);
  q0 = fmaf(s0b.x, s0b.x, q0); q0 = fmaf(s0b.y, s0b.y, q0);
  q1 = fmaf(s1b.x, s1b.x, q1); q1 = fmaf(s1b.y, s1b.y, q1);
  q2 = fmaf(s2b.x, s2b.x, q2); q2 = fmaf(s2b.y, s2b.y, q2);
  q3 = fmaf(s3b.x, s3b.x, q3); q3 = fmaf(s3b.y, s3b.y, q3);
  q0 = fmaf(s0b.z, s0b.z, q0); q0 = fmaf(s0b.w, s0b.w, q0);
  q1 = fmaf(s1b.z, s1b.z, q1); q1 = fmaf(s1b.w, s1b.w, q1);
  q2 = fmaf(s2b.z, s2b.z, q2); q2 = fmaf(s2b.w, s2b.w, q2);
  q3 = fmaf(s3b.z, s3b.z, q3); q3 = fmaf(s3b.w, s3b.w, q3);
  q0 = dpp_add<0xB1>(q0);  q1 = dpp_add<0xB1>(q1);
  q2 = dpp_add<0xB1>(q2);  q3 = dpp_add<0xB1>(q3);
  q0 = dpp_add<0x4E>(q0);  q1 = dpp_add<0x4E>(q1);
  q2 = dpp_add<0x4E>(q2);  q3 = dpp_add<0x4E>(q3);
  q0 = dpp_add<0x141>(q0); q1 = dpp_add<0x141>(q1);
  q2 = dpp_add<0x141>(q2); q3 = dpp_add<0x141>(q3);

  __syncthreads();

  // --- min over all 16 windows of (xnorm_w - 2*dot(x_w, s_n)).
  // Hot loop UNCHANGED from the 68.8us version (proven spill-free, DS/VALU
  // balanced, SQ_LDS_BANK_CONFLICT = 0).
  float best0 = FLT_MAX, best1 = FLT_MAX, best2 = FLT_MAX, best3 = FLT_MAX;
  for (int w = 0; w < WPB; ++w) {
    const float4* xr = (const float4*)(xs + (size_t)w * L + oct * 8);
    const float4 xa = xr[0];
    const float4 xb = xr[1];

    float d0 = xa.x * s0a.x + xa.y * s0a.y;
    float d1 = xa.x * s1a.x + xa.y * s1a.y;
    float d2 = xa.x * s2a.x + xa.y * s2a.y;
    float d3 = xa.x * s3a.x + xa.y * s3a.y;
    d0 = fmaf(xa.z, s0a.z, d0); d0 = fmaf(xa.w, s0a.w, d0);
    d1 = fmaf(xa.z, s1a.z, d1); d1 = fmaf(xa.w, s1a.w, d1);
    d2 = fmaf(xa.z, s2a.z, d2); d2 = fmaf(xa.w, s2a.w, d2);
    d3 = fmaf(xa.z, s3a.z, d3); d3 = fmaf(xa.w, s3a.w, d3);
    d0 = fmaf(xb.x, s0b.x, d0); d0 = fmaf(xb.y, s0b.y, d0);
    d1 = fmaf(xb.x, s1b.x, d1); d1 = fmaf(xb.y, s1b.y, d1);
    d2 = fmaf(xb.x, s2b.x, d2); d2 = fmaf(xb.y, s2b.y, d2);
    d3 = fmaf(xb.x, s3b.x, d3); d3 = fmaf(xb.y, s3b.y, d3);
    d0 = fmaf(xb.z, s0b.z, d0); d0 = fmaf(xb.w, s0b.w, d0);
    d1 = fmaf(xb.z, s1b.z, d1); d1 = fmaf(xb.w, s1b.w, d1);
    d2 = fmaf(xb.z, s2b.z, d2); d2 = fmaf(xb.w, s2b.w, d2);
    d3 = fmaf(xb.z, s3b.z, d3); d3 = fmaf(xb.w, s3b.w, d3);

    d0 = dpp_add<0xB1>(d0);  d1 = dpp_add<0xB1>(d1);
    d2 = dpp_add<0xB1>(d2);  d3 = dpp_add<0xB1>(d3);
    d0 = dpp_add<0x4E>(d0);  d1 = dpp_add<0x4E>(d1);
    d2 = dpp_add<0x4E>(d2);  d3 = dpp_add<0x4E>(d3);
    d0 = dpp_add<0x141>(d0); d1 = dpp_add<0x141>(d1);
    d2 = dpp_add<0x141>(d2); d3 = dpp_add<0x141>(d3);

    const float xn = xnorm_s[w];
    best0 = fminf(best0, fmaf(-2.f, d0, xn));
    best1 = fminf(best1, fmaf(-2.f, d1, xn));
    best2 = fminf(best2, fmaf(-2.f, d2, xn));
    best3 = fminf(best3, fmaf(-2.f, d3, xn));
  }

  // --- oct-leader writes 4 consecutive chunk-mins (with +||s||^2 folded in).
  if (oct == 0) {
    float4 o;
    o.x = best0 + q0; o.y = best1 + q1; o.z = best2 + q2; o.w = best3 + q3;
    *(float4*)(part + ((size_t)b * NC + c) * N + n0) = o;
  }

  // --- Arrival: __syncthreads drains vmcnt(0) for the whole block (all part
  // stores at least in this XCD's L2); tid0's release fence writes the L2
  // back device-wide, then device-scope atomicAdd.
  __syncthreads();
  if (tid == 0) {
    __threadfence();
    int done = atomicAdd(&g_cnt[b], 1);
    s_last = (done == NC - 1) ? 1 : 0;
    if (done == NC - 1) atomicExch(&g_cnt[b], 0);  // restore for next launch
  }
  __syncthreads();
  if (!s_last) return;

  // --- Last block for this b: classifier head. All 256 threads alive
  // (uniform branch on shared s_last) so barriers below are safe.
  __threadfence();  // acquire: invalidate stale L1/L2 lines before reading
                    // other XCDs' part writes
  float v = 0.f;
  if (tid < N) {
    const float* pb = part + (size_t)b * NC * N + tid;
    float m = FLT_MAX;
#pragma unroll
    for (int cc = 0; cc < NC; ++cc) m = fminf(m, pb[cc * N]);
    float d2 = fmaxf(m, 0.f);  // guard fp rounding before sqrt
    v = sqrtf(d2) * cls_w[tid];
  }
#pragma unroll
  for (int off = 32; off > 0; off >>= 1) v += __shfl_down(v, off, 64);
  if ((tid & 63) == 0) red[tid >> 6] = v;
  __syncthreads();
  if (tid == 0) {
    float z = red[0] + red[1] + red[2] + red[3] + cls_b[0];
    out[b] = 1.0f / (1.0f + expf(-z));
  }
}

extern "C" void kernel_launch(void* const* d_in, const int* in_sizes, int n_in,
                              void* d_out, int out_size, void* d_ws,
                              size_t ws_size, hipStream_t stream) {
  const float* x = (const float*)d_in[0];      // [B, W, L]
  const float* shp = (const float*)d_in[1];    // [N, L]
  const float* cls_w = (const float*)d_in[2];  // [1, N]
  const float* cls_b = (const float*)d_in[3];  // [1]
  float* out = (float*)d_out;                  // [B, 1]
  float* part = (float*)d_ws;                  // [B, NC, N] fp32 (512 KB)

  shapelet_fused_kernel<<<B * NC, 256, 0, stream>>>(x, shp, cls_w, cls_b,
                                                    part, out);
}

// Round 2
// 68.825 us; speedup vs baseline: 1.3486x; 1.3486x over previous
//
#include <hip/hip_runtime.h>
#include <cfloat>
#include <cmath>

// x[B,W,L], shapelets[N,L], cls_w[1,N], cls_b[1]
constexpr int B = 64;
constexpr int W = 256;
constexpr int N = 128;
constexpr int L = 64;
constexpr int NC = 16;        // window-chunks per batch element
constexpr int WPB = W / NC;   // 16 windows per block

// Arrival counters for the last-block-per-b head. Zero-initialized at module
// load; the last block restores its counter to 0 so every launch (and every
// rocprof counter-replay) starts from a clean state. No spin-waits anywhere,
// so no deadlock risk; only the last-arriving block proceeds to the tail.
__device__ int g_cnt[B];

// VALU-pipe cross-lane add (DPP), avoiding the DS pipe entirely.
// CTRL: 0xB1 = quad_perm xor1, 0x4E = quad_perm xor2,
//       0x141 = row_half_mirror (xor-4 class), 0x140 = row_mirror (xor-8).
template <int CTRL>
__device__ __forceinline__ float dpp_add(float v) {
  return v + __int_as_float(__builtin_amdgcn_update_dpp(
                 0, __float_as_int(v), CTRL, 0xF, 0xF, true));
}

// ---------------------------------------------------------------------------
// FUSED kernel, round 2. R1 post-mortem: VALUBusy(13%) x dur(45us) = 5.9us of
// VALU — exactly the expected compute — so the hot loop was intact and the
// 39us balance was STALL on the per-block __threadfence() (agent release =
// buffer_wbl2 sc1 = 4MiB L2 tag-walk writeback, x1024 blocks, serialized per
// XCD, with 3 waves/block parked at the next barrier while it drains).
//
// Fix: NO cache-maintenance instructions at all. Cross-XCD visibility of
// part[] comes from agent-scope (sc1) write-through stores + agent-scope
// loads in the reader. Ordering store->arrival comes for free: hipcc emits
// s_waitcnt vmcnt(0) before the s_barrier of the __syncthreads() that
// precedes the arrival atomicAdd (all waves' sc1 stores are at the coherent
// point before tid0 arrives). Arrival itself is a RELAXED agent atomicAdd.
//
// grid = B*NC = 1024 blocks of 256 = exactly 4 blocks/CU, co-resident.
// ---------------------------------------------------------------------------
__global__ __launch_bounds__(256)
void shapelet_fused_kernel(const float* __restrict__ x,
                           const float* __restrict__ shp,
                           const float* __restrict__ cls_w,
                           const float* __restrict__ cls_b,
                           float* __restrict__ part,
                           float* __restrict__ out) {
  __shared__ float xs[WPB * L];   // 4 KB
  __shared__ float xnorm_s[WPB];
  __shared__ int s_last;
  __shared__ float red[4];

  const int b = blockIdx.x >> 4;
  const int c = blockIdx.x & 15;
  const int tid = threadIdx.x;
  const int oct = tid & 7;        // eighth-of-row owned by this lane
  const int grp = tid >> 3;       // 0..31 -> shapelets 4*grp..4*grp+3
  const int n0 = grp * 4;

  // --- Stage x[b, c*16:(c+1)*16, :]: one float4/thread; ||x_w||^2 via a
  // 16-lane DPP reduction (16 float4 per window) — zero DS-pipe swizzles.
  {
    const float4* xg =
        (const float4*)(x + ((size_t)b * W + (size_t)c * WPB) * L);
    float4 v = xg[tid];
    ((float4*)xs)[tid] = v;
    float p = v.x * v.x + v.y * v.y + v.z * v.z + v.w * v.w;
    p = dpp_add<0xB1>(p);    // xor1 (quad)
    p = dpp_add<0x4E>(p);    // xor2 (quad)
    p = dpp_add<0x141>(p);   // 4<->8 within row of 16
    p = dpp_add<0x140>(p);   // mirror row of 16
    if ((tid & 15) == 0) xnorm_s[tid >> 4] = p;
  }

  // --- Eighth-rows of 4 shapelets: 8 NAMED float4 (32 VGPRs). No arrays.
  const float4* g0 = (const float4*)(shp + (size_t)(n0 + 0) * L + oct * 8);
  const float4* g1 = (const float4*)(shp + (size_t)(n0 + 1) * L + oct * 8);
  const float4* g2 = (const float4*)(shp + (size_t)(n0 + 2) * L + oct * 8);
  const float4* g3 = (const float4*)(shp + (size_t)(n0 + 3) * L + oct * 8);
  const float4 s0a = g0[0], s0b = g0[1];
  const float4 s1a = g1[0], s1b = g1[1];
  const float4 s2a = g2[0], s2b = g2[1];
  const float4 s3a = g3[0], s3b = g3[1];

  // --- ||s_n||^2 once per block via the same 8-lane DPP tree. Only consumed
  // at the part-write after the loop, so regalloc may spill q0..q3 to scratch
  // across the loop — one store+reload outside the hot path, harmless (this
  // is what R1's VGPR_Count=52 was).
  float q0 = s0a.x * s0a.x + s0a.y * s0a.y;
  float q1 = s1a.x * s1a.x + s1a.y * s1a.y;
  float q2 = s2a.x * s2a.x + s2a.y * s2a.y;
  float q3 = s3a.x * s3a.x + s3a.y * s3a.y;
  q0 = fmaf(s0a.z, s0a.z, q0); q0 = fmaf(s0a.w, s0a.w, q0);
  q1 = fmaf(s1a.z, s1a.z, q1); q1 = fmaf(s1a.w, s1a.w, q1);
  q2 = fmaf(s2a.z, s2a.z, q2); q2 = fmaf(s2a.w, s2a.w, q2);
  q3 = fmaf(s3a.z, s3a.z, q3); q3 = fmaf(s3a.w, s3a.w, q3);
  q0 = fmaf(s0b.x, s0b.x, q0); q0 = fmaf(s0b.y, s0b.y, q0);
  q1 = fmaf(s1b.x, s1b.x, q1); q1 = fmaf(s1b.y, s1b.y, q1);
  q2 = fmaf(s2b.x, s2b.x, q2); q2 = fmaf(s2b.y, s2b.y, q2);
  q3 = fmaf(s3b.x, s3b.x, q3); q3 = fmaf(s3b.y, s3b.y, q3);
  q0 = fmaf(s0b.z, s0b.z, q0); q0 = fmaf(s0b.w, s0b.w, q0);
  q1 = fmaf(s1b.z, s1b.z, q1); q1 = fmaf(s1b.w, s1b.w, q1);
  q2 = fmaf(s2b.z, s2b.z, q2); q2 = fmaf(s2b.w, s2b.w, q2);
  q3 = fmaf(s3b.z, s3b.z, q3); q3 = fmaf(s3b.w, s3b.w, q3);
  q0 = dpp_add<0xB1>(q0);  q1 = dpp_add<0xB1>(q1);
  q2 = dpp_add<0x4E>(q2);  q3 = dpp_add<0xB1>(q3);
  // (note: full 3-stage tree for each; stages below)
  q0 = dpp_add<0x4E>(q0);  q1 = dpp_add<0x4E>(q1);
  q2 = dpp_add<0xB1>(q2);  q3 = dpp_add<0x4E>(q3);
  q0 = dpp_add<0x141>(q0); q1 = dpp_add<0x141>(q1);
  q2 = dpp_add<0x141>(q2); q3 = dpp_add<0x141>(q3);

  __syncthreads();

  // --- min over all 16 windows of (xnorm_w - 2*dot(x_w, s_n)).
  // Hot loop UNCHANGED from the proven 68.8us k1 (spill-free, DS/VALU
  // balanced, SQ_LDS_BANK_CONFLICT = 0).
  float best0 = FLT_MAX, best1 = FLT_MAX, best2 = FLT_MAX, best3 = FLT_MAX;
  for (int w = 0; w < WPB; ++w) {
    const float4* xr = (const float4*)(xs + (size_t)w * L + oct * 8);
    const float4 xa = xr[0];
    const float4 xb = xr[1];

    float d0 = xa.x * s0a.x + xa.y * s0a.y;
    float d1 = xa.x * s1a.x + xa.y * s1a.y;
    float d2 = xa.x * s2a.x + xa.y * s2a.y;
    float d3 = xa.x * s3a.x + xa.y * s3a.y;
    d0 = fmaf(xa.z, s0a.z, d0); d0 = fmaf(xa.w, s0a.w, d0);
    d1 = fmaf(xa.z, s1a.z, d1); d1 = fmaf(xa.w, s1a.w, d1);
    d2 = fmaf(xa.z, s2a.z, d2); d2 = fmaf(xa.w, s2a.w, d2);
    d3 = fmaf(xa.z, s3a.z, d3); d3 = fmaf(xa.w, s3a.w, d3);
    d0 = fmaf(xb.x, s0b.x, d0); d0 = fmaf(xb.y, s0b.y, d0);
    d1 = fmaf(xb.x, s1b.x, d1); d1 = fmaf(xb.y, s1b.y, d1);
    d2 = fmaf(xb.x, s2b.x, d2); d2 = fmaf(xb.y, s2b.y, d2);
    d3 = fmaf(xb.x, s3b.x, d3); d3 = fmaf(xb.y, s3b.y, d3);
    d0 = fmaf(xb.z, s0b.z, d0); d0 = fmaf(xb.w, s0b.w, d0);
    d1 = fmaf(xb.z, s1b.z, d1); d1 = fmaf(xb.w, s1b.w, d1);
    d2 = fmaf(xb.z, s2b.z, d2); d2 = fmaf(xb.w, s2b.w, d2);
    d3 = fmaf(xb.z, s3b.z, d3); d3 = fmaf(xb.w, s3b.w, d3);

    d0 = dpp_add<0xB1>(d0);  d1 = dpp_add<0xB1>(d1);
    d2 = dpp_add<0xB1>(d2);  d3 = dpp_add<0xB1>(d3);
    d0 = dpp_add<0x4E>(d0);  d1 = dpp_add<0x4E>(d1);
    d2 = dpp_add<0x4E>(d2);  d3 = dpp_add<0x4E>(d3);
    d0 = dpp_add<0x141>(d0); d1 = dpp_add<0x141>(d1);
    d2 = dpp_add<0x141>(d2); d3 = dpp_add<0x141>(d3);

    const float xn = xnorm_s[w];
    best0 = fminf(best0, fmaf(-2.f, d0, xn));
    best1 = fminf(best1, fmaf(-2.f, d1, xn));
    best2 = fminf(best2, fmaf(-2.f, d2, xn));
    best3 = fminf(best3, fmaf(-2.f, d3, xn));
  }

  // --- oct-leader writes 4 chunk-mins (+||s||^2 folded) as AGENT-scope
  // (sc1) write-through stores: visible across XCDs without any wbl2.
  if (oct == 0) {
    float* p = part + ((size_t)b * NC + c) * N + n0;
    __hip_atomic_store(p + 0, best0 + q0, __ATOMIC_RELAXED,
                       __HIP_MEMORY_SCOPE_AGENT);
    __hip_atomic_store(p + 1, best1 + q1, __ATOMIC_RELAXED,
                       __HIP_MEMORY_SCOPE_AGENT);
    __hip_atomic_store(p + 2, best2 + q2, __ATOMIC_RELAXED,
                       __HIP_MEMORY_SCOPE_AGENT);
    __hip_atomic_store(p + 3, best3 + q3, __ATOMIC_RELAXED,
                       __HIP_MEMORY_SCOPE_AGENT);
  }

  // --- Arrival. The __syncthreads() below compiles to s_waitcnt vmcnt(0)
  // lgkmcnt(0) + s_barrier in EVERY wave, so all sc1 part-stores of the
  // block are at the agent-coherent point before tid0's (relaxed, agent)
  // arrival add. No fence instructions anywhere.
  __syncthreads();
  if (tid == 0) {
    int done = __hip_atomic_fetch_add(&g_cnt[b], 1, __ATOMIC_RELAXED,
                                      __HIP_MEMORY_SCOPE_AGENT);
    s_last = (done == NC - 1) ? 1 : 0;
    if (done == NC - 1)
      __hip_atomic_store(&g_cnt[b], 0, __ATOMIC_RELAXED,
                         __HIP_MEMORY_SCOPE_AGENT);  // clean for next launch
  }
  __syncthreads();
  if (!s_last) return;

  // --- Last block for this b: classifier head. All 256 threads alive
  // (uniform branch on shared s_last) so the barrier below is safe.
  // part reads are agent-scope loads (bypass this XCD's possibly-stale
  // L1/L2); everything they read was written through with sc1.
  float v = 0.f;
  if (tid < N) {
    const float* pb = part + (size_t)b * NC * N + tid;
    float m = FLT_MAX;
#pragma unroll
    for (int cc = 0; cc < NC; ++cc) {
      float pv = __hip_atomic_load(pb + cc * N, __ATOMIC_RELAXED,
                                   __HIP_MEMORY_SCOPE_AGENT);
      m = fminf(m, pv);
    }
    float d2 = fmaxf(m, 0.f);  // guard fp rounding before sqrt
    v = sqrtf(d2) * cls_w[tid];
  }
#pragma unroll
  for (int off = 32; off > 0; off >>= 1) v += __shfl_down(v, off, 64);
  if ((tid & 63) == 0) red[tid >> 6] = v;
  __syncthreads();
  if (tid == 0) {
    float z = red[0] + red[1] + red[2] + red[3] + cls_b[0];
    out[b] = 1.0f / (1.0f + expf(-z));
  }
}

extern "C" void kernel_launch(void* const* d_in, const int* in_sizes, int n_in,
                              void* d_out, int out_size, void* d_ws,
                              size_t ws_size, hipStream_t stream) {
  const float* x = (const float*)d_in[0];      // [B, W, L]
  const float* shp = (const float*)d_in[1];    // [N, L]
  const float* cls_w = (const float*)d_in[2];  // [1, N]
  const float* cls_b = (const float*)d_in[3];  // [1]
  float* out = (float*)d_out;                  // [B, 1]
  float* part = (float*)d_ws;                  // [B, NC, N] fp32 (512 KB)

  shapelet_fused_kernel<<<B * NC, 256, 0, stream>>>(x, shp, cls_w, cls_b,
                                                    part, out);
}